// Round 10
// baseline (580.970 us; speedup 1.0000x reference)
//
#include <hip/hip_runtime.h>
#include <math.h>

#define IC     2401
#define BSZ    256
#define OC     8
#define CS     16
#define OCC    128     // OC*CS
#define XROW   19208   // x row length (floats) = IC*8
#define KP     19264   // padded K (=301*64), pad zeroed
#define KTILES 301
#define NI     64      // split-K slices for S phase
#define NBLK   256     // persistent grid: 256 blocks x 256 threads (<=1/CU => co-resident)

typedef __attribute__((ext_vector_type(8))) short short8;
typedef __attribute__((ext_vector_type(4))) float f32x4;

__device__ __forceinline__ unsigned short f2bf(float f) {
    union { float f; unsigned u; } v; v.f = f;
    const unsigned r = v.u + 0x7FFF + ((v.u >> 16) & 1);   // RNE
    return (unsigned short)(r >> 16);
}
__device__ __forceinline__ float bf2f(unsigned short h) {
    union { unsigned u; float f; } v; v.u = ((unsigned)h) << 16;
    return v.f;
}

// ---- device-wide barrier: release fence -> counter -> spin -> acquire fence.
// Safe: all NBLK blocks are co-resident (grid <= 1 block/CU capacity).
__device__ __forceinline__ void gbar(unsigned* ctr, unsigned target, int tid)
{
    __threadfence();                       // release: drain stores + L2 writeback
    __syncthreads();                       // whole block's stores flushed
    if (tid == 0) {
        __hip_atomic_fetch_add(ctr, 1u, __ATOMIC_RELAXED, __HIP_MEMORY_SCOPE_AGENT);
        while (__hip_atomic_load(ctr, __ATOMIC_RELAXED, __HIP_MEMORY_SCOPE_AGENT) < target)
            __builtin_amdgcn_s_sleep(8);
    }
    __syncthreads();
    __threadfence();                       // acquire: invalidate L1/L2
}

// ---------------- prep: xT[k][b], xB[b][k], Wbf/cwt0 [oc][k] (bf16) ----------
__device__ void phase_prep(char* sm, int blk, int tid,
                           const float* __restrict__ x, const float* __restrict__ W,
                           unsigned short* xT, unsigned short* xB,
                           unsigned short* Wbf, unsigned short* cwt)
{
    float* Ts = (float*)sm;                // [64][65] = 16640 B
#pragma unroll 1
    for (int r = 0; r < 5; ++r) {
        const int job = blk + NBLK * r;
        if (job < 1204) {
            const int bg = job & 3;        // b-group of 64
            const int kt = job >> 2;       // k-tile 0..300
            __syncthreads();
#pragma unroll
            for (int q = 0; q < 4; ++q) {
                const int flat = q * 256 + tid;
                const int b = flat >> 4, cq = flat & 15;
                const int col = kt * 64 + cq * 4;
                float4 v = make_float4(0.f, 0.f, 0.f, 0.f);
                if (col < XROW) v = *(const float4*)(x + (size_t)(bg * 64 + b) * XROW + col);
                *(float4*)&Ts[b * 65 + cq * 4] = v;
            }
            __syncthreads();
#pragma unroll
            for (int q = 0; q < 2; ++q) {  // xT[k][b]
                const int flat = q * 256 + tid;
                const int rl = flat >> 3, bq = flat & 7;
                union { short8 v; unsigned short h[8]; } o;
#pragma unroll
                for (int j = 0; j < 8; ++j) o.h[j] = f2bf(Ts[(bq * 8 + j) * 65 + rl]);
                *(short8*)(xT + (size_t)(kt * 64 + rl) * 256 + bg * 64 + bq * 8) = o.v;
            }
#pragma unroll
            for (int q = 0; q < 2; ++q) {  // xB[b][k]
                const int flat = q * 256 + tid;
                const int b = flat >> 3, g = flat & 7;
                union { short8 v; unsigned short h[8]; } o;
#pragma unroll
                for (int j = 0; j < 8; ++j) o.h[j] = f2bf(Ts[b * 65 + g * 8 + j]);
                *(short8*)(xB + (size_t)(bg * 64 + b) * KP + (size_t)kt * 64 + g * 8) = o.v;
            }
        }
    }
    float* Ws = (float*)sm;                // [8][1032] = 33024 B
#pragma unroll 1
    for (int r = 0; r < 2; ++r) {
        const int job = blk + NBLK * r;
        if (job < KTILES) {
            const int i0 = job * 8;
            __syncthreads();
#pragma unroll
            for (int q = 0; q < 8; ++q) {
                const int flat = q * 256 + tid;
                const int g = flat >> 8, rem = flat & 255;
                int gi = i0 + g; if (gi > 2400) gi = 2400;
                *(float4*)&Ws[g * 1032 + rem * 4] = *(const float4*)(W + (size_t)gi * 1024 + rem * 4);
            }
            __syncthreads();
#pragma unroll
            for (int q = 0; q < 4; ++q) {
                const int flat = q * 256 + tid;
                const int oc = flat >> 3, g = flat & 7;
                const int gi = i0 + g;
                union { short8 v; unsigned short h[8]; } w, c;
                if (gi <= 2400) {
                    const float* wp = &Ws[g * 1032 + oc * 8];
#pragma unroll
                    for (int j = 0; j < 8; ++j) { w.h[j] = f2bf(wp[j]); c.h[j] = f2bf(0.125f * wp[j]); }
                } else {
#pragma unroll
                    for (int j = 0; j < 8; ++j) { w.h[j] = 0; c.h[j] = 0; }
                }
                *(short8*)(Wbf + (size_t)oc * KP + (size_t)gi * 8) = w.v;
                *(short8*)(cwt + (size_t)oc * KP + (size_t)gi * 8) = c.v;
            }
        }
    }
}

// ---------------- S: barrier-free MFMA split-K, fragments straight from global -----
__device__ void phase_s(int blk, int tid,
                        const unsigned short* __restrict__ xB,
                        const unsigned short* __restrict__ cwt, float* spart)
{
    const int bg = blk & 3, iy = blk >> 2;
    const int w  = tid >> 6;
    const int ln = tid & 63;
    const int mr = ln & 15, qd = ln >> 4;
    const int m0 = bg * 64 + w * 16;

    const unsigned short* ap = xB + (size_t)(m0 + mr) * KP + qd * 8;
    const unsigned short* bp = cwt + (size_t)mr * KP + qd * 8;

    f32x4 acc[8];
#pragma unroll
    for (int n = 0; n < 8; ++n) acc[n] = (f32x4){0.f, 0.f, 0.f, 0.f};

#pragma unroll 1
    for (int kt = iy; kt < KTILES; kt += NI) {
        const int kbase = kt * 64;
#pragma unroll
        for (int kk = 0; kk < 2; ++kk) {
            const int k = kbase + kk * 32;
            const short8 a = *(const short8*)(ap + k);
#pragma unroll
            for (int nt = 0; nt < 8; ++nt) {
                const short8 b = *(const short8*)(bp + (size_t)(nt * 16) * KP + k);
                acc[nt] = __builtin_amdgcn_mfma_f32_16x16x32_bf16(a, b, acc[nt], 0, 0, 0);
            }
        }
    }

    float* op = spart + (size_t)iy * (BSZ * OCC);
#pragma unroll
    for (int nt = 0; nt < 8; ++nt)
#pragma unroll
        for (int r = 0; r < 4; ++r)
            op[(size_t)(m0 + qd * 4 + r) * OCC + nt * 16 + mr] = acc[nt][r];
}

// ---------------- V: reduce NI slices + squash -> vT bf16 or out fp32 --------------
__device__ void phase_v(char* sm, int blk, int tid, const float* __restrict__ spart,
                        unsigned short* vT, float* out, int writeT)
{
    float* red = (float*)sm;               // [256]
    const int r0  = blk * 8;               // 8 (b,o)-rows per block
    const int idx = tid & 127;
    const int k0  = tid >> 7;

    const float* base = spart + (size_t)r0 * 16 + idx;
    float acc = 0.0f;
#pragma unroll 8
    for (int k = k0; k < NI; k += 2) acc += base[(size_t)k * (BSZ * OCC)];
    __syncthreads();                       // sm reuse safety
    red[tid] = acc;
    __syncthreads();

    if (tid < 128) {
        const float s = red[tid] + red[tid + 128];
        float ms = s * s;
        ms += __shfl_xor(ms, 1); ms += __shfl_xor(ms, 2);
        ms += __shfl_xor(ms, 4); ms += __shfl_xor(ms, 8);
        const float scale = sqrtf(ms) / (1.0f + ms);   // == mag_sq/(1+mag_sq)/mag
        const float outv = s * scale;
        const int row = r0 + (tid >> 4);   // = b*8 + o
        const int j   = tid & 15;
        if (writeT) vT[(size_t)((row & 7) * 16 + j) * 256 + (row >> 3)] = f2bf(outv);
        else        out[(size_t)row * 16 + j] = outv;
    }
}

// ---------------- A: H = vT*xT^T (MFMA), a=(1/256)sum W*H, softmax, cwt=c*Wbf -------
__device__ void a_job(char* sm, int jb, int tid, int first,
                      const unsigned short* __restrict__ xT,
                      const unsigned short* __restrict__ vT,
                      const unsigned short* __restrict__ Wbf,
                      float* bij, unsigned short* cwt)
{
    unsigned short* As = (unsigned short*)sm;            // [128 oc][64 b]
    unsigned short* Bx = (unsigned short*)(sm + 16384);  // [64 (i,d)][64 b]
    float* Hs = (float*)sm;                              // [128][68] aliased

    const int i0 = jb * 8;
    const int ln = tid & 63, wv = tid >> 6;
    const int mr = ln & 15, qd = ln >> 4;

    f32x4 acc[2][4];
#pragma unroll
    for (int a = 0; a < 2; ++a)
#pragma unroll
        for (int b = 0; b < 4; ++b) acc[a][b] = (f32x4){0.f, 0.f, 0.f, 0.f};

#pragma unroll 1
    for (int bc = 0; bc < 4; ++bc) {
        __syncthreads();
#pragma unroll
        for (int r = 0; r < 4; ++r) {          // As <- vT tile
            const int flat = r * 256 + tid;
            const int oc = flat >> 3, col = flat & 7;
            const short8 v = *(const short8*)(vT + (size_t)oc * 256 + bc * 64 + col * 8);
            *(short8*)&As[oc * 64 + ((col ^ (oc & 7)) * 8)] = v;
        }
#pragma unroll
        for (int r = 0; r < 2; ++r) {          // Bx <- xT rows i0*8..+63
            const int flat = r * 256 + tid;
            const int rw = flat >> 3, col = flat & 7;
            const short8 v = *(const short8*)(xT + (size_t)(i0 * 8 + rw) * 256 + bc * 64 + col * 8);
            *(short8*)&Bx[rw * 64 + ((col ^ (rw & 7)) * 8)] = v;
        }
        __syncthreads();
#pragma unroll
        for (int kk = 0; kk < 2; ++kk) {
            const int csw = ((kk * 4 + qd) ^ (mr & 7)) * 8;
#pragma unroll
            for (int nt = 0; nt < 4; ++nt) {
                const short8 b = *(const short8*)&Bx[(nt * 16 + mr) * 64 + csw];
#pragma unroll
                for (int mt = 0; mt < 2; ++mt) {
                    const short8 a = *(const short8*)&As[((wv * 2 + mt) * 16 + mr) * 64 + csw];
                    acc[mt][nt] = __builtin_amdgcn_mfma_f32_16x16x32_bf16(a, b, acc[mt][nt], 0, 0, 0);
                }
            }
        }
    }

    __syncthreads();
#pragma unroll
    for (int mt = 0; mt < 2; ++mt)
#pragma unroll
        for (int nt = 0; nt < 4; ++nt)
#pragma unroll
            for (int r = 0; r < 4; ++r)
                Hs[((wv * 2 + mt) * 16 + qd * 4 + r) * 68 + nt * 16 + mr] = acc[mt][nt][r];
    __syncthreads();

    // phase 2: tid = il*32 + oo*4 + ch
    const int ch = tid & 3, oo = (tid >> 2) & 7, il = tid >> 5;
    const int ival = i0 + il;
    const int gi = (ival < IC) ? ival : IC - 1;
    const unsigned short* Wt = Wbf + (size_t)(oo * 16 + ch * 4) * KP + (size_t)gi * 8;

    float wreg[4][8];
#pragma unroll
    for (int c = 0; c < 4; ++c) {
        union { short8 v; unsigned short h[8]; } uw;
        uw.v = *(const short8*)(Wt + (size_t)c * KP);
#pragma unroll
        for (int j = 0; j < 8; ++j) wreg[c][j] = bf2f(uw.h[j]);
    }
    float p = 0.0f;
#pragma unroll
    for (int c = 0; c < 4; ++c) {
        const float* hr = &Hs[(oo * 16 + ch * 4 + c) * 68 + il * 8];
        const float4 h0 = *(const float4*)hr;
        const float4 h1 = *(const float4*)(hr + 4);
        p = fmaf(wreg[c][0], h0.x, p); p = fmaf(wreg[c][1], h0.y, p);
        p = fmaf(wreg[c][2], h0.z, p); p = fmaf(wreg[c][3], h0.w, p);
        p = fmaf(wreg[c][4], h1.x, p); p = fmaf(wreg[c][5], h1.y, p);
        p = fmaf(wreg[c][6], h1.z, p); p = fmaf(wreg[c][7], h1.w, p);
    }
    p += __shfl_xor(p, 1); p += __shfl_xor(p, 2);   // combine ch quarters
    const float anew = p * (1.0f / 256.0f);
    float bv = anew;
    if (!first) bv += bij[gi * 8 + oo];
    float mx = bv;                                   // softmax over oo (bits 2..4)
    mx = fmaxf(mx, __shfl_xor(mx, 4));
    mx = fmaxf(mx, __shfl_xor(mx, 8));
    mx = fmaxf(mx, __shfl_xor(mx, 16));
    const float e = expf(bv - mx);
    float ss = e;
    ss += __shfl_xor(ss, 4); ss += __shfl_xor(ss, 8); ss += __shfl_xor(ss, 16);
    float cv = e / ss;
    if (ival >= IC) cv = 0.0f;                       // keep cwt pad rows zero
    if (ch == 0 && ival < IC) bij[ival * 8 + oo] = bv;
#pragma unroll
    for (int c = 0; c < 4; ++c) {
        union { short8 v; unsigned short h[8]; } o;
#pragma unroll
        for (int j = 0; j < 8; ++j) o.h[j] = f2bf(cv * wreg[c][j]);
        *(short8*)(cwt + (size_t)(oo * 16 + ch * 4 + c) * KP + (size_t)ival * 8) = o.v;
    }
}

// ================= persistent mega-kernel (9 dispatches -> 1) =======================
__global__ __launch_bounds__(256, 2)
void mega_kernel(const float* __restrict__ x, const float* __restrict__ W,
                 float* __restrict__ out,
                 unsigned short* xT, unsigned short* xB, unsigned short* Wbf,
                 unsigned short* cwt, unsigned short* vT, float* bij,
                 float* spart, unsigned* ctr)
{
    __shared__ __align__(16) char sm[34816];
    const int blk = blockIdx.x, tid = threadIdx.x;
    unsigned bar = 0;

    phase_prep(sm, blk, tid, x, W, xT, xB, Wbf, cwt);
    bar += NBLK; gbar(ctr, bar, tid);

#pragma unroll 1
    for (int it = 0; it < 3; ++it) {
        phase_s(blk, tid, xB, cwt, spart);
        bar += NBLK; gbar(ctr, bar, tid);
        phase_v(sm, blk, tid, spart, vT, out, it < 2);
        if (it == 2) break;
        bar += NBLK; gbar(ctr, bar, tid);
#pragma unroll 1
        for (int jb = blk; jb < KTILES; jb += NBLK)
            a_job(sm, jb, tid, it == 0, xT, vT, Wbf, bij, cwt);
        bar += NBLK; gbar(ctr, bar, tid);
    }
}

extern "C" void kernel_launch(void* const* d_in, const int* in_sizes, int n_in,
                              void* d_out, int out_size, void* d_ws, size_t ws_size,
                              hipStream_t stream)
{
    const float* x = (const float*)d_in[0];   // [256, 2401, 8]
    const float* W = (const float*)d_in[1];   // [2401, 8, 16, 8]
    float* out = (float*)d_out;               // [256, 8, 16]

    char* p = (char*)d_ws;
    unsigned*       ctr   = (unsigned*)p;       p += 256;                          // 1 counter (64B-pad)
    float*          spart = (float*)p;          p += (size_t)NI * BSZ * OCC * 4;   // 8.39 MB
    unsigned short* xT    = (unsigned short*)p; p += (size_t)KP * 256 * 2;         // 9.86 MB
    unsigned short* xB    = (unsigned short*)p; p += (size_t)256 * KP * 2;         // 9.86 MB
    unsigned short* Wbf   = (unsigned short*)p; p += (size_t)128 * KP * 2;         // 4.93 MB
    unsigned short* cwt   = (unsigned short*)p; p += (size_t)128 * KP * 2;         // 4.93 MB
    unsigned short* vT    = (unsigned short*)p; p += (size_t)128 * 256 * 2;        // 64 KB
    float*          bij   = (float*)p;                                            // 77 KB

    (void)hipMemsetAsync(ctr, 0, 256, stream);   // graph-capturable (memset node)

    mega_kernel<<<NBLK, 256, 0, stream>>>(x, W, out, xT, xB, Wbf, cwt, vT, bij,
                                          spart, ctr);
}